// Round 3
// baseline (236.259 us; speedup 1.0000x reference)
//
#include <hip/hip_runtime.h>
#include <hip/hip_bf16.h>

typedef __bf16 bf16;
typedef __bf16 bf16x8 __attribute__((ext_vector_type(8)));
typedef float f32x4 __attribute__((ext_vector_type(4)));

#define MFMA16(a, b, c) __builtin_amdgcn_mfma_f32_16x16x32_bf16((a), (b), (c), 0, 0, 0)

// Problem: B=2, L=4096, D=1024, H=8, Hd=128, CHUNK=64, NCHUNK=64
// gamma_h = 1 - 2^(-5-h).  Inputs fp32, OUTPUT fp32.

// async 16B global->LDS (gfx950). LDS dest is wave-uniform base + lane*16.
__device__ __forceinline__ void g2l16(const bf16* g, bf16* l) {
  __builtin_amdgcn_global_load_lds(
      (const __attribute__((address_space(1))) void*)g,
      (__attribute__((address_space(3))) void*)l, 16, 0, 0);
}

// Transpose-safe LDS index, stride-72 rows (bf16).
__device__ __forceinline__ int swz72(int row, int c) {
  return row * 72 + (c & 7) + ((((c >> 3) ^ (row >> 3)) & 7) << 3);
}

// ---------------------------------------------------------------------------
// prep: fused {fp32->bf16 convert of X} + {transpose+cvt of the 4 weights}.
// ---------------------------------------------------------------------------
__global__ __launch_bounds__(256) void prep(
    const float* __restrict__ X, const float* __restrict__ Wq,
    const float* __restrict__ Wk, const float* __restrict__ Wv,
    const float* __restrict__ Wo, bf16* __restrict__ Xb,
    bf16* __restrict__ Wt) {
  __shared__ bf16 t[64 * 72];
  const int tid = threadIdx.x;
  if (blockIdx.x < 4096) {
    const size_t i = ((size_t)blockIdx.x * 256 + tid) * 8;
    float4 a = *(const float4*)&X[i];
    float4 b = *(const float4*)&X[i + 4];
    union { bf16 h[8]; uint4 u; } p;
    p.h[0] = (bf16)a.x; p.h[1] = (bf16)a.y; p.h[2] = (bf16)a.z; p.h[3] = (bf16)a.w;
    p.h[4] = (bf16)b.x; p.h[5] = (bf16)b.y; p.h[6] = (bf16)b.z; p.h[7] = (bf16)b.w;
    *(uint4*)&Xb[i] = p.u;
    return;
  }
  const int bid2 = blockIdx.x - 4096;          // 0..1023
  const int bx = bid2 & 15, by = (bid2 >> 4) & 15, bz = bid2 >> 8;
  const float* src = (bz == 0) ? Wq : (bz == 1) ? Wk : (bz == 2) ? Wv : Wo;
  bf16* dst = Wt + (size_t)bz * 1024 * 1024;
  const int k0 = bx * 64, n0 = by * 64;
#pragma unroll
  for (int s = 0; s < 4; ++s) {
    int u = tid + s * 256;          // 0..1023
    int r = u >> 4, c4 = (u & 15) * 4;
    float4 f = *(const float4*)&src[(size_t)(k0 + r) * 1024 + n0 + c4];
    t[r * 72 + c4 + 0] = (bf16)f.x;
    t[r * 72 + c4 + 1] = (bf16)f.y;
    t[r * 72 + c4 + 2] = (bf16)f.z;
    t[r * 72 + c4 + 3] = (bf16)f.w;
  }
  __syncthreads();
#pragma unroll
  for (int s = 0; s < 2; ++s) {
    int u = tid + s * 256;
    int r = u >> 3, cc = u & 7;     // output row n0+r, k-chunk cc
    union { bf16 h[8]; uint4 u4; } pk;
#pragma unroll
    for (int j = 0; j < 8; ++j) pk.h[j] = t[(cc * 8 + j) * 72 + r];
    *(uint4*)&dst[(size_t)(n0 + r) * 1024 + k0 + cc * 8] = pk.u4;
  }
}

// ---------------------------------------------------------------------------
// 8-phase 256x256 GEMM (m201 template port): C = alpha * (A @ Bt^T).
// A: 8192x1024 bf16, Bt: B^T row-major (QKV: 3072 fused rows), C: bf16 slices.
// BK=64, 8 waves (2M x 4N), per-wave out 128x64, acc[8][4] f32x4.
// LDS: 2 K-tile buffers x (A 256x64 + B 256x64) bf16 = 128 KiB, 1 block/CU.
// Per iteration: 8 phases over 2 K-tiles (even tile->buf0, odd->buf1 FIXED).
// Phase = {ds_read quadrant frags (A/B reg-reuse) | stage 1 half-tile |
//          s_barrier | lgkmcnt(0) | setprio(1) 16 MFMA setprio(0) | s_barrier}
// vmcnt(6) ONLY at phases 4 and 8 (6 = 2 loads x 3 half-tiles in flight).
// Half-tile staging windows (stage strictly after region's last read; retired
// by a vmcnt before its first read) verified for steady state + prologue +
// tails: p1:(U,A1) p2:(V,A0) p3:(V,B0) p4:(V,A1) p5:(V,B1) p6:(W,A0)
// p7:(W,B0) p8:(W,B1), where T=2t(buf0) U=2t+1(buf1) V=2t+2 W=2t+3.
// Last iter (t=7): V,W stages off; p4 uses vmcnt(0).
// XOR-chunk swizzle (proven 0-conflict): phys chunk = logical ^ (row&7).
// ---------------------------------------------------------------------------
template <typename TC, int QKV>
__global__ __launch_bounds__(512, 2) void gemm_8p(
    const bf16* __restrict__ A, const bf16* __restrict__ Bt,
    TC* __restrict__ C, float alpha) {
  __shared__ bf16 lds[2 * 32768];  // per buf: A @ 0, B @ 16384 (elements)
  const int m0 = blockIdx.x * 256;
  const int n0g = blockIdx.y * 256;
  int ncol0 = n0g;
  if (QKV) {
    const int z = n0g >> 10;
    C += (size_t)z * (8192 * 1024);
    if (z != 0) alpha = 1.0f;
    ncol0 = n0g & 1023;
  }
  const int tid = threadIdx.x;
  const int w = tid >> 6, lane = tid & 63, lr = lane & 15, quad = lane >> 4;
  const int wm = w >> 2, wn = w & 3;
  const int l8 = lane >> 3;                    // staging row-within-8
  const int clog = (lane & 7) ^ l8;            // pre-swizzled 16B chunk
  const bf16* gA = A + (size_t)(m0 + l8) * 1024 + clog * 8;
  const bf16* gB = Bt + (size_t)(n0g + l8) * 1024 + clog * 8;

  // Stage A-half mh of K-tile tt into buffer bi (2 g2l16/thread, 8 rows/wave
  // per call; bb = w + s*8 selects the 8-row group).
#define SA(tt, bi, mh) do {                                                  \
    { const int r_ = (mh)*64 + (w & 7)*8;                                    \
      g2l16(gA + (size_t)r_*1024 + (tt)*64, &lds[(bi)*32768 + r_*64]); }     \
    { const int r_ = (mh)*64 + (w & 7)*8 + 128;                              \
      g2l16(gA + (size_t)r_*1024 + (tt)*64, &lds[(bi)*32768 + r_*64]); }     \
  } while (0)
  // Stage B-half nh: rows (bb>>2)*64 + nh*32 + (bb&3)*8, bb = w and w+8.
#define SB(tt, bi, nh) do {                                                  \
    { const int bb = w;                                                      \
      const int r_ = (bb>>2)*64 + (nh)*32 + (bb&3)*8;                        \
      g2l16(gB + (size_t)r_*1024 + (tt)*64,                                  \
            &lds[(bi)*32768 + 16384 + r_*64]); }                             \
    { const int bb = w + 8;                                                  \
      const int r_ = (bb>>2)*64 + (nh)*32 + (bb&3)*8;                        \
      g2l16(gB + (size_t)r_*1024 + (tt)*64,                                  \
            &lds[(bi)*32768 + 16384 + r_*64]); }                             \
  } while (0)
#define LA_(dst, bi, mh)                                                     \
  _Pragma("unroll") for (int i = 0; i < 4; ++i)                              \
  _Pragma("unroll") for (int kk = 0; kk < 2; ++kk)                           \
    dst[i][kk] = *(const bf16x8*)&lds[(bi)*32768 +                           \
        (wm*128 + (mh)*64 + i*16 + lr)*64 + (((kk*4+quad)^(lr&7))*8)];
#define LB_(dst, bi, nh)                                                     \
  _Pragma("unroll") for (int j = 0; j < 2; ++j)                              \
  _Pragma("unroll") for (int kk = 0; kk < 2; ++kk)                           \
    dst[j][kk] = *(const bf16x8*)&lds[(bi)*32768 + 16384 +                   \
        (wn*64 + (nh)*32 + j*16 + lr)*64 + (((kk*4+quad)^(lr&7))*8)];
#define MM_(mh, nh, Af, Bf)                                                  \
  __builtin_amdgcn_s_setprio(1);                                             \
  _Pragma("unroll") for (int i = 0; i < 4; ++i)                              \
  _Pragma("unroll") for (int j = 0; j < 2; ++j)                              \
  _Pragma("unroll") for (int kk = 0; kk < 2; ++kk)                           \
    acc[(mh)*4+i][(nh)*2+j] =                                                \
        MFMA16(Af[i][kk], Bf[j][kk], acc[(mh)*4+i][(nh)*2+j]);               \
  __builtin_amdgcn_s_setprio(0);
#define BAR   asm volatile("s_barrier" ::: "memory")
#define LGKM0 asm volatile("s_waitcnt lgkmcnt(0)" ::: "memory")
#define VM6   asm volatile("s_waitcnt vmcnt(6)" ::: "memory")
#define VM0   asm volatile("s_waitcnt vmcnt(0)" ::: "memory")

  f32x4 acc[8][4] = {};
  bf16x8 a_[4][2], b0_[2][2], b1_[2][2];

  // Prologue: tile0 full (4 oldest -> retired by vmcnt(6)) + tile1 {A0,B0,B1}.
  SA(0, 0, 0); SB(0, 0, 0); SA(0, 0, 1); SB(0, 0, 1);
  SA(1, 1, 0); SB(1, 1, 0); SB(1, 1, 1);
  VM6; BAR;

#pragma unroll 1
  for (int t = 0; t < 8; ++t) {
    // ---- p1: quad(0,0) of buf0 ----
    LA_(a_, 0, 0); LB_(b0_, 0, 0);
    SA(2 * t + 1, 1, 1);                       // (U, A1)
    BAR; LGKM0; MM_(0, 0, a_, b0_); BAR;
    // ---- p2: quad(0,1), reuse A ----
    LB_(b1_, 0, 1);
    if (t < 7) SA(2 * t + 2, 0, 0);            // (V, A0)
    BAR; LGKM0; MM_(0, 1, a_, b1_); BAR;
    // ---- p3: quad(1,0), reuse B0 ----
    LA_(a_, 0, 1);
    if (t < 7) SB(2 * t + 2, 0, 0);            // (V, B0)
    BAR; LGKM0; MM_(1, 0, a_, b0_); BAR;
    // ---- p4: quad(1,1), all reuse ----
    if (t < 7) SA(2 * t + 2, 0, 1);            // (V, A1)
    BAR; LGKM0; MM_(1, 1, a_, b1_);
    if (t < 7) { VM6; } else { VM0; }
    BAR;
    // ---- p5: quad(0,0) of buf1 ----
    LA_(a_, 1, 0); LB_(b0_, 1, 0);
    if (t < 7) SB(2 * t + 2, 0, 1);            // (V, B1)
    BAR; LGKM0; MM_(0, 0, a_, b0_); BAR;
    // ---- p6 ----
    LB_(b1_, 1, 1);
    if (t < 7) SA(2 * t + 3, 1, 0);            // (W, A0)
    BAR; LGKM0; MM_(0, 1, a_, b1_); BAR;
    // ---- p7 ----
    LA_(a_, 1, 1);
    if (t < 7) SB(2 * t + 3, 1, 0);            // (W, B0)
    BAR; LGKM0; MM_(1, 0, a_, b0_); BAR;
    // ---- p8 ----
    if (t < 7) SB(2 * t + 3, 1, 1);            // (W, B1)
    BAR; LGKM0; MM_(1, 1, a_, b1_);
    VM6;                                       // t=7: nothing outstanding
    BAR;
  }
#undef SA
#undef SB
#undef LA_
#undef LB_
#undef MM_
#undef BAR
#undef LGKM0
#undef VM6
#undef VM0

  // Epilogue: D layout col=lane&15, row=quad*4+r
#pragma unroll
  for (int a = 0; a < 8; ++a) {
#pragma unroll
    for (int b = 0; b < 4; ++b) {
      const int row = m0 + wm * 128 + (a >> 2) * 64 + (a & 3) * 16 + quad * 4;
      const int col = ncol0 + wn * 64 + (b >> 1) * 32 + (b & 1) * 16 + lr;
#pragma unroll
      for (int r = 0; r < 4; ++r)
        C[(size_t)(row + r) * 1024 + col] = (TC)(acc[a][b][r] * alpha);
    }
  }
}

// ---------------------------------------------------------------------------
// GEMM (proven 128x128, 858 TF): used for the output projection.
// ---------------------------------------------------------------------------
template <typename TC, int QKV>
__global__ __launch_bounds__(256) void gemm_lds(
    const bf16* __restrict__ A, const bf16* __restrict__ Bt,
    TC* __restrict__ C, float alpha) {
  __shared__ bf16 lA[128 * 64];
  __shared__ bf16 lB[128 * 64];
  const int m0 = blockIdx.x * 128, n0 = blockIdx.y * 128;
  if (QKV) {
    Bt += (size_t)blockIdx.z * 1024 * 1024;
    C += (size_t)blockIdx.z * 8192 * 1024;
    if (blockIdx.z != 0) alpha = 1.0f;
  }
  const int tid = threadIdx.x;
  const int w = tid >> 6, lane = tid & 63, lr = lane & 15, quad = lane >> 4;
  const int wm = w >> 1, wn = w & 1;

  const int srow = w * 32 + (lane >> 3);              // row for issue 0
  const int clog = (lane & 7) ^ ((lane >> 3) & 7);    // swizzled 16B chunk
  const bf16* gA = A + (size_t)(m0 + srow) * 1024 + clog * 8;
  const bf16* gB = Bt + (size_t)(n0 + srow) * 1024 + clog * 8;

  f32x4 acc[4][4] = {};

  for (int it = 0; it < 16; ++it) {
    const int k0 = it * 64;
#pragma unroll
    for (int is = 0; is < 4; ++is) {
      g2l16(gA + (size_t)is * 8 * 1024 + k0, &lA[(w * 32 + is * 8) * 64]);
      g2l16(gB + (size_t)is * 8 * 1024 + k0, &lB[(w * 32 + is * 8) * 64]);
    }
    __syncthreads();
#pragma unroll
    for (int kk = 0; kk < 2; ++kk) {
      bf16x8 af[4], bfv[4];
#pragma unroll
      for (int i = 0; i < 4; ++i) {
        const int m = wm * 64 + i * 16 + lr;
        af[i] = *(bf16x8*)&lA[m * 64 + (((kk * 4 + quad) ^ (lr & 7)) * 8)];
      }
#pragma unroll
      for (int j = 0; j < 4; ++j) {
        const int n = wn * 64 + j * 16 + lr;
        bfv[j] = *(bf16x8*)&lB[n * 64 + (((kk * 4 + quad) ^ (lr & 7)) * 8)];
      }
#pragma unroll
      for (int i = 0; i < 4; ++i)
#pragma unroll
        for (int j = 0; j < 4; ++j)
          acc[i][j] = MFMA16(af[i], bfv[j], acc[i][j]);
    }
    __syncthreads();
  }
#pragma unroll
  for (int i = 0; i < 4; ++i) {
#pragma unroll
    for (int j = 0; j < 4; ++j) {
      const int row = m0 + wm * 64 + i * 16 + quad * 4;
      const int col = n0 + wn * 64 + j * 16 + lr;
#pragma unroll
      for (int r = 0; r < 4; ++r)
        C[(size_t)(row + r) * 1024 + col] = (TC)(acc[i][j][r] * alpha);
    }
  }
}

// ---------------------------------------------------------------------------
// Phase A: per-(b,h,chunk) T^T[dv][dk] = sum_c k[c][dk]*g^(63-c)*v[c][dv]
// ---------------------------------------------------------------------------
__global__ __launch_bounds__(256) void chunk_kv(
    const bf16* __restrict__ kb, const bf16* __restrict__ vb,
    bf16* __restrict__ Tb) {
  __shared__ bf16 lK[128 * 72];  // [dk][c] with decay folded in (swizzled)
  __shared__ bf16 lV[128 * 72];  // [dv][c] (swizzled)
  const int g = blockIdx.x;
  const int bh = g >> 6, n = g & 63, b = bh >> 3, h = bh & 7;
  const float log2g = log2f(1.0f - exp2f(-5.0f - (float)h));
  const int tid = threadIdx.x;
  const size_t rowbase = (size_t)(b * 4096 + n * 64) * 1024 + h * 128;
  const bf16* kc = kb + rowbase;
  const bf16* vc = vb + rowbase;
#pragma unroll
  for (int s = 0; s < 4; ++s) {
    int u = tid + s * 256;
    int c = u >> 4, d0 = (u & 15) * 8;
    union { uint4 u4; bf16 h8[8]; } kv, vv;
    kv.u4 = *(const uint4*)&kc[(size_t)c * 1024 + d0];
    vv.u4 = *(const uint4*)&vc[(size_t)c * 1024 + d0];
    const float dec = exp2f((float)(63 - c) * log2g);
#pragma unroll
    for (int j = 0; j < 8; ++j) {
      lK[swz72(d0 + j, c)] = (bf16)((float)kv.h8[j] * dec);
      lV[swz72(d0 + j, c)] = vv.h8[j];
    }
  }
  __syncthreads();
  const int w = tid >> 6, lane = tid & 63, lr = lane & 15, quad = lane >> 4;
  const int wm = w >> 1, wn = w & 1;
  f32x4 acc[4][4] = {};
#pragma unroll
  for (int kk = 0; kk < 2; ++kk) {
    bf16x8 af[4], bv[4];
#pragma unroll
    for (int i = 0; i < 4; ++i)
      af[i] = *(bf16x8*)&lK[swz72(wm * 64 + i * 16 + lr, kk * 32 + quad * 8)];
#pragma unroll
    for (int j = 0; j < 4; ++j)
      bv[j] = *(bf16x8*)&lV[swz72(wn * 64 + j * 16 + lr, kk * 32 + quad * 8)];
#pragma unroll
    for (int i = 0; i < 4; ++i)
#pragma unroll
      for (int j = 0; j < 4; ++j)
        acc[i][j] = MFMA16(af[i], bv[j], acc[i][j]);
  }
  bf16* tchunk = Tb + (size_t)g * 16384;
#pragma unroll
  for (int i = 0; i < 4; ++i) {
#pragma unroll
    for (int j = 0; j < 4; ++j) {
      const int dk = wm * 64 + i * 16 + quad * 4;  // row of T (r advances dk)
      const int dv = wn * 64 + j * 16 + lr;        // col of T
      union { bf16 h4[4]; uint2 u2; } pk;
#pragma unroll
      for (int r = 0; r < 4; ++r) pk.h4[r] = (bf16)acc[i][j][r];
      *(uint2*)&tchunk[(size_t)dv * 128 + dk] = pk.u2;  // transposed store
    }
  }
}

// ---------------------------------------------------------------------------
// Phase B: in-place exclusive prefix scan over chunks (x8 vectorized).
// ---------------------------------------------------------------------------
__global__ __launch_bounds__(256) void scan_state(bf16* __restrict__ Tb) {
  const int blk = blockIdx.x;               // 0..127
  const int bh = blk >> 3, seg = blk & 7, h = bh & 7;
  const float gs = exp2f(64.0f * log2f(1.0f - exp2f(-5.0f - (float)h)));
  const size_t base = (size_t)bh * 64 * 16384 + (size_t)seg * 2048 +
                      (size_t)threadIdx.x * 8;
  float S[8] = {0.f, 0.f, 0.f, 0.f, 0.f, 0.f, 0.f, 0.f};
#pragma unroll 4
  for (int n = 0; n < 64; ++n) {
    const size_t a = base + (size_t)n * 16384;
    union { uint4 u4; bf16 h8[8]; } in, out;
    in.u4 = *(const uint4*)&Tb[a];
#pragma unroll
    for (int e = 0; e < 8; ++e) {
      out.h8[e] = (bf16)S[e];
      S[e] = gs * S[e] + (float)in.h8[e];
    }
    *(uint4*)&Tb[a] = out.u4;
  }
}

// ---------------------------------------------------------------------------
// Phase C: per-(b,h,chunk) output:
// P = (q@k^T) * D(mask/decay);  o = P@v + (q * g^(i+1)) @ S_prev
// ---------------------------------------------------------------------------
__global__ __launch_bounds__(256) void chunk_out(
    const bf16* __restrict__ qb, const bf16* __restrict__ kb,
    const bf16* __restrict__ vb, const bf16* __restrict__ Sp,
    bf16* __restrict__ ob) {
  __shared__ bf16 lQ[64 * 136];   // [c][dk]
  __shared__ bf16 lQd[64 * 136];  // [c][dk] * gamma^(c+1)
  __shared__ bf16 lK[64 * 136];   // [c][dk]
  __shared__ bf16 lVt[128 * 72];  // [dv][c] (swizzled)
  __shared__ bf16 lP[64 * 72];    // [ci][cj] masked scores
  const int g = blockIdx.x;
  const int bh = g >> 6, n = g & 63, b = bh >> 3, h = bh & 7;
  const float log2g = log2f(1.0f - exp2f(-5.0f - (float)h));
  const int tid = threadIdx.x;
  const size_t rowbase = (size_t)(b * 4096 + n * 64) * 1024 + h * 128;
  const bf16* qc = qb + rowbase;
  const bf16* kc = kb + rowbase;
  const bf16* vc = vb + rowbase;
#pragma unroll
  for (int s = 0; s < 4; ++s) {
    int u = tid + s * 256;
    int c = u >> 4, d0 = (u & 15) * 8;
    union { uint4 u4; bf16 h8[8]; } qv, vv, qd;
    qv.u4 = *(const uint4*)&qc[(size_t)c * 1024 + d0];
    *(uint4*)&lQ[c * 136 + d0] = qv.u4;
    *(uint4*)&lK[c * 136 + d0] = *(const uint4*)&kc[(size_t)c * 1024 + d0];
    const float dq = exp2f((float)(c + 1) * log2g);
#pragma unroll
    for (int j = 0; j < 8; ++j) qd.h8[j] = (bf16)((float)qv.h8[j] * dq);
    *(uint4*)&lQd[c * 136 + d0] = qd.u4;
    vv.u4 = *(const uint4*)&vc[(size_t)c * 1024 + d0];
#pragma unroll
    for (int j = 0; j < 8; ++j) lVt[swz72(d0 + j, c)] = vv.h8[j];
  }
  __syncthreads();
  const int w = tid >> 6, lane = tid & 63, lr = lane & 15, quad = lane >> 4;

  // --- Step 1: P = q @ k^T; wave w computes columns [w*16, w*16+16) ---
  f32x4 p[4] = {};
#pragma unroll
  for (int kk = 0; kk < 4; ++kk) {
    bf16x8 bfrag = *(bf16x8*)&lK[(w * 16 + lr) * 136 + kk * 32 + quad * 8];
#pragma unroll
    for (int i = 0; i < 4; ++i) {
      bf16x8 afrag = *(bf16x8*)&lQ[(i * 16 + lr) * 136 + kk * 32 + quad * 8];
      p[i] = MFMA16(afrag, bfrag, p[i]);
    }
  }
  // mask + decay, write to lP (bf16)
#pragma unroll
  for (int i = 0; i < 4; ++i) {
#pragma unroll
    for (int r = 0; r < 4; ++r) {
      const int row = i * 16 + quad * 4 + r;
      const int col = w * 16 + lr;
      const int diff = row - col;
      const float val =
          (diff >= 0) ? p[i][r] * exp2f((float)diff * log2g) : 0.0f;
      lP[row * 72 + col] = (bf16)val;
    }
  }
  __syncthreads();

  // --- Step 2: o_intra = P @ v; wave w covers dv in [w*32, w*32+32) ---
  f32x4 oacc[4][2] = {};
#pragma unroll
  for (int j = 0; j < 2; ++j) {
    const int dvt = w * 32 + j * 16;
#pragma unroll
    for (int kk = 0; kk < 2; ++kk) {
      bf16x8 bfrag = *(bf16x8*)&lVt[swz72(dvt + lr, kk * 32 + quad * 8)];
#pragma unroll
      for (int i = 0; i < 4; ++i) {
        bf16x8 afrag = *(bf16x8*)&lP[(i * 16 + lr) * 72 + kk * 32 + quad * 8];
        oacc[i][j] = MFMA16(afrag, bfrag, oacc[i][j]);
      }
    }
  }

  // --- Step 3: o_inter = (q_decayed) @ S_prev ---
  const bf16* sp = Sp + (size_t)g * 16384;
#pragma unroll
  for (int kk = 0; kk < 4; ++kk) {
    bf16x8 aN[4];
#pragma unroll
    for (int i = 0; i < 4; ++i)
      aN[i] = *(bf16x8*)&lQd[(i * 16 + lr) * 136 + kk * 32 + quad * 8];
#pragma unroll
    for (int j = 0; j < 2; ++j) {
      bf16x8 bfrag =
          *(const bf16x8*)&sp[(size_t)(w * 32 + j * 16 + lr) * 128 + kk * 32 + quad * 8];
#pragma unroll
      for (int i = 0; i < 4; ++i) oacc[i][j] = MFMA16(aN[i], bfrag, oacc[i][j]);
    }
  }

  // --- write o chunk ---
  bf16* oc = ob + rowbase;
#pragma unroll
  for (int i = 0; i < 4; ++i)
#pragma unroll
    for (int j = 0; j < 2; ++j)
#pragma unroll
      for (int r = 0; r < 4; ++r) {
        const int row = i * 16 + quad * 4 + r;
        const int col = w * 32 + j * 16 + lr;
        oc[(size_t)row * 1024 + col] = (bf16)oacc[i][j][r];
      }
}

// ---------------------------------------------------------------------------
extern "C" void kernel_launch(void* const* d_in, const int* in_sizes, int n_in,
                              void* d_out, int out_size, void* d_ws,
                              size_t ws_size, hipStream_t stream) {
  const float* X  = (const float*)d_in[0];
  const float* Wq = (const float*)d_in[2];
  const float* Wk = (const float*)d_in[3];
  const float* Wv = (const float*)d_in[4];
  const float* Wo = (const float*)d_in[5];

  char* ws = (char*)d_ws;
  const size_t SZ_QKV = (size_t)8192 * 1024 * sizeof(bf16);  // 16 MiB each
  bf16* qb = (bf16*)(ws);                                    // q,k,v contiguous
  bf16* ob = (bf16*)(ws + 3 * SZ_QKV);
  bf16* Tb = (bf16*)(ws + 4 * SZ_QKV);                       // 32 MiB
  bf16* Wt = (bf16*)(ws + 6 * SZ_QKV);                       // 8 MiB
  bf16* Xb = (bf16*)(ws + 6 * SZ_QKV + (size_t)4 * 1024 * 1024 * sizeof(bf16));
  bf16* kb = qb + (size_t)8192 * 1024;
  bf16* vb = kb + (size_t)8192 * 1024;

  prep<<<5120, 256, 0, stream>>>(X, Wq, Wk, Wv, Wo, Xb, Wt);

  const float qscale = 0.08838834764831845f;  // 128^-0.5
  // fused q/k/v projection: Wt rows 0..3071 = one 3072-row B^T; y picks slice
  gemm_8p<bf16, 1><<<dim3(32, 12), 512, 0, stream>>>(Xb, Wt, qb, qscale);

  chunk_kv<<<1024, 256, 0, stream>>>(kb, vb, Tb);
  scan_state<<<128, 256, 0, stream>>>(Tb);
  chunk_out<<<1024, 256, 0, stream>>>(qb, kb, vb, Tb, ob);

  gemm_lds<float, 0><<<dim3(64, 8), 256, 0, stream>>>(
      ob, Wt + (size_t)3 * 1024 * 1024, (float*)d_out, 1.0f);
}

// Round 4
// 234.357 us; speedup vs baseline: 1.0081x; 1.0081x over previous
//
#include <hip/hip_runtime.h>
#include <hip/hip_bf16.h>

typedef __bf16 bf16;
typedef __bf16 bf16x8 __attribute__((ext_vector_type(8)));
typedef float f32x4 __attribute__((ext_vector_type(4)));

#define MFMA16(a, b, c) __builtin_amdgcn_mfma_f32_16x16x32_bf16((a), (b), (c), 0, 0, 0)

// Problem: B=2, L=4096, D=1024, H=8, Hd=128, CHUNK=64, NCHUNK=64
// gamma_h = 1 - 2^(-5-h).  Inputs fp32, OUTPUT fp32.

// async 16B global->LDS (gfx950). LDS dest is wave-uniform base + lane*16.
__device__ __forceinline__ void g2l16(const bf16* g, bf16* l) {
  __builtin_amdgcn_global_load_lds(
      (const __attribute__((address_space(1))) void*)g,
      (__attribute__((address_space(3))) void*)l, 16, 0, 0);
}

// Transpose-safe LDS index, stride-72 rows (bf16).
__device__ __forceinline__ int swz72(int row, int c) {
  return row * 72 + (c & 7) + ((((c >> 3) ^ (row >> 3)) & 7) << 3);
}

// ---------------------------------------------------------------------------
// prep: fused {fp32->bf16 convert of X} + {transpose+cvt of the 4 weights}.
// ---------------------------------------------------------------------------
__global__ __launch_bounds__(256) void prep(
    const float* __restrict__ X, const float* __restrict__ Wq,
    const float* __restrict__ Wk, const float* __restrict__ Wv,
    const float* __restrict__ Wo, bf16* __restrict__ Xb,
    bf16* __restrict__ Wt) {
  __shared__ bf16 t[64 * 72];
  const int tid = threadIdx.x;
  if (blockIdx.x < 4096) {
    const size_t i = ((size_t)blockIdx.x * 256 + tid) * 8;
    float4 a = *(const float4*)&X[i];
    float4 b = *(const float4*)&X[i + 4];
    union { bf16 h[8]; uint4 u; } p;
    p.h[0] = (bf16)a.x; p.h[1] = (bf16)a.y; p.h[2] = (bf16)a.z; p.h[3] = (bf16)a.w;
    p.h[4] = (bf16)b.x; p.h[5] = (bf16)b.y; p.h[6] = (bf16)b.z; p.h[7] = (bf16)b.w;
    *(uint4*)&Xb[i] = p.u;
    return;
  }
  const int bid2 = blockIdx.x - 4096;          // 0..1023
  const int bx = bid2 & 15, by = (bid2 >> 4) & 15, bz = bid2 >> 8;
  const float* src = (bz == 0) ? Wq : (bz == 1) ? Wk : (bz == 2) ? Wv : Wo;
  bf16* dst = Wt + (size_t)bz * 1024 * 1024;
  const int k0 = bx * 64, n0 = by * 64;
#pragma unroll
  for (int s = 0; s < 4; ++s) {
    int u = tid + s * 256;          // 0..1023
    int r = u >> 4, c4 = (u & 15) * 4;
    float4 f = *(const float4*)&src[(size_t)(k0 + r) * 1024 + n0 + c4];
    t[r * 72 + c4 + 0] = (bf16)f.x;
    t[r * 72 + c4 + 1] = (bf16)f.y;
    t[r * 72 + c4 + 2] = (bf16)f.z;
    t[r * 72 + c4 + 3] = (bf16)f.w;
  }
  __syncthreads();
#pragma unroll
  for (int s = 0; s < 2; ++s) {
    int u = tid + s * 256;
    int r = u >> 3, cc = u & 7;     // output row n0+r, k-chunk cc
    union { bf16 h[8]; uint4 u4; } pk;
#pragma unroll
    for (int j = 0; j < 8; ++j) pk.h[j] = t[(cc * 8 + j) * 72 + r];
    *(uint4*)&dst[(size_t)(n0 + r) * 1024 + k0 + cc * 8] = pk.u4;
  }
}

// ---------------------------------------------------------------------------
// GEMM: C = alpha * (A @ Bt^T).  A: M x 1024 bf16 row-major,
// Bt: 1024 x 1024 bf16 = B^T row-major, C: M x 1024 (TC = bf16 or fp32).
// 128x128 tile, BK=64, 4 waves. global_load_lds(16B) staging with XOR-swizzle.
// PROVEN structure (858 TF here). Both deep-pipeline variants (3-buf 2-phase,
// 256^2 8-phase) regressed (-7%/-11%) -> GEMM schedule axis closed.
// If QKV!=0: gridDim.z selects Wt slice z and output slice z (q gets alpha).
// ---------------------------------------------------------------------------
template <typename TC, int QKV>
__global__ __launch_bounds__(256) void gemm_lds(
    const bf16* __restrict__ A, const bf16* __restrict__ Bt,
    TC* __restrict__ C, float alpha) {
  __shared__ bf16 lA[128 * 64];
  __shared__ bf16 lB[128 * 64];
  const int m0 = blockIdx.x * 128, n0 = blockIdx.y * 128;
  if (QKV) {
    Bt += (size_t)blockIdx.z * 1024 * 1024;
    C += (size_t)blockIdx.z * 8192 * 1024;
    if (blockIdx.z != 0) alpha = 1.0f;
  }
  const int tid = threadIdx.x;
  const int w = tid >> 6, lane = tid & 63, lr = lane & 15, quad = lane >> 4;
  const int wm = w >> 1, wn = w & 1;

  const int srow = w * 32 + (lane >> 3);              // row for issue 0
  const int clog = (lane & 7) ^ ((lane >> 3) & 7);    // swizzled 16B chunk
  const bf16* gA = A + (size_t)(m0 + srow) * 1024 + clog * 8;
  const bf16* gB = Bt + (size_t)(n0 + srow) * 1024 + clog * 8;

  f32x4 acc[4][4] = {};

  for (int it = 0; it < 16; ++it) {
    const int k0 = it * 64;
#pragma unroll
    for (int is = 0; is < 4; ++is) {
      g2l16(gA + (size_t)is * 8 * 1024 + k0, &lA[(w * 32 + is * 8) * 64]);
      g2l16(gB + (size_t)is * 8 * 1024 + k0, &lB[(w * 32 + is * 8) * 64]);
    }
    __syncthreads();
#pragma unroll
    for (int kk = 0; kk < 2; ++kk) {
      bf16x8 af[4], bfv[4];
#pragma unroll
      for (int i = 0; i < 4; ++i) {
        const int m = wm * 64 + i * 16 + lr;
        af[i] = *(bf16x8*)&lA[m * 64 + (((kk * 4 + quad) ^ (lr & 7)) * 8)];
      }
#pragma unroll
      for (int j = 0; j < 4; ++j) {
        const int n = wn * 64 + j * 16 + lr;
        bfv[j] = *(bf16x8*)&lB[n * 64 + (((kk * 4 + quad) ^ (lr & 7)) * 8)];
      }
#pragma unroll
      for (int i = 0; i < 4; ++i)
#pragma unroll
        for (int j = 0; j < 4; ++j)
          acc[i][j] = MFMA16(af[i], bfv[j], acc[i][j]);
    }
    __syncthreads();
  }
#pragma unroll
  for (int i = 0; i < 4; ++i) {
#pragma unroll
    for (int j = 0; j < 4; ++j) {
      const int row = m0 + wm * 64 + i * 16 + quad * 4;
      const int col = n0 + wn * 64 + j * 16 + lr;
#pragma unroll
      for (int r = 0; r < 4; ++r)
        C[(size_t)(row + r) * 1024 + col] = (TC)(acc[i][j][r] * alpha);
    }
  }
}

// ---------------------------------------------------------------------------
// Phase A: per-(b,h,chunk) T^T[dv][dk] = sum_c k[c][dk]*g^(63-c)*v[c][dv]
// Both operands need c-contiguous fragments -> genuine LDS transposes (swz72).
// ---------------------------------------------------------------------------
__global__ __launch_bounds__(256) void chunk_kv(
    const bf16* __restrict__ kb, const bf16* __restrict__ vb,
    bf16* __restrict__ Tb) {
  __shared__ bf16 lK[128 * 72];  // [dk][c] with decay folded in (swizzled)
  __shared__ bf16 lV[128 * 72];  // [dv][c] (swizzled)
  const int g = blockIdx.x;
  const int bh = g >> 6, n = g & 63, b = bh >> 3, h = bh & 7;
  const float log2g = log2f(1.0f - exp2f(-5.0f - (float)h));
  const int tid = threadIdx.x;
  const size_t rowbase = (size_t)(b * 4096 + n * 64) * 1024 + h * 128;
  const bf16* kc = kb + rowbase;
  const bf16* vc = vb + rowbase;
#pragma unroll
  for (int s = 0; s < 4; ++s) {
    int u = tid + s * 256;
    int c = u >> 4, d0 = (u & 15) * 8;
    union { uint4 u4; bf16 h8[8]; } kv, vv;
    kv.u4 = *(const uint4*)&kc[(size_t)c * 1024 + d0];
    vv.u4 = *(const uint4*)&vc[(size_t)c * 1024 + d0];
    const float dec = exp2f((float)(63 - c) * log2g);
#pragma unroll
    for (int j = 0; j < 8; ++j) {
      lK[swz72(d0 + j, c)] = (bf16)((float)kv.h8[j] * dec);
      lV[swz72(d0 + j, c)] = vv.h8[j];
    }
  }
  __syncthreads();
  const int w = tid >> 6, lane = tid & 63, lr = lane & 15, quad = lane >> 4;
  const int wm = w >> 1, wn = w & 1;
  f32x4 acc[4][4] = {};
#pragma unroll
  for (int kk = 0; kk < 2; ++kk) {
    bf16x8 af[4], bv[4];
#pragma unroll
    for (int i = 0; i < 4; ++i)
      af[i] = *(bf16x8*)&lK[swz72(wm * 64 + i * 16 + lr, kk * 32 + quad * 8)];
#pragma unroll
    for (int j = 0; j < 4; ++j)
      bv[j] = *(bf16x8*)&lV[swz72(wn * 64 + j * 16 + lr, kk * 32 + quad * 8)];
#pragma unroll
    for (int i = 0; i < 4; ++i)
#pragma unroll
      for (int j = 0; j < 4; ++j)
        acc[i][j] = MFMA16(af[i], bv[j], acc[i][j]);
  }
  bf16* tchunk = Tb + (size_t)g * 16384;
#pragma unroll
  for (int i = 0; i < 4; ++i) {
#pragma unroll
    for (int j = 0; j < 4; ++j) {
      const int dk = wm * 64 + i * 16 + quad * 4;  // row of T (r advances dk)
      const int dv = wn * 64 + j * 16 + lr;        // col of T
      union { bf16 h4[4]; uint2 u2; } pk;
#pragma unroll
      for (int r = 0; r < 4; ++r) pk.h4[r] = (bf16)acc[i][j][r];
      *(uint2*)&tchunk[(size_t)dv * 128 + dk] = pk.u2;  // transposed store
    }
  }
}

// ---------------------------------------------------------------------------
// Phase B: in-place exclusive prefix scan over chunks (x8 vectorized).
// unroll 8: loads are S-independent -> 8 in flight hides the HBM round-trip.
// ---------------------------------------------------------------------------
__global__ __launch_bounds__(256) void scan_state(bf16* __restrict__ Tb) {
  const int blk = blockIdx.x;               // 0..127
  const int bh = blk >> 3, seg = blk & 7, h = bh & 7;
  const float gs = exp2f(64.0f * log2f(1.0f - exp2f(-5.0f - (float)h)));
  const size_t base = (size_t)bh * 64 * 16384 + (size_t)seg * 2048 +
                      (size_t)threadIdx.x * 8;
  float S[8] = {0.f, 0.f, 0.f, 0.f, 0.f, 0.f, 0.f, 0.f};
#pragma unroll 8
  for (int n = 0; n < 64; ++n) {
    const size_t a = base + (size_t)n * 16384;
    union { uint4 u4; bf16 h8[8]; } in, out;
    in.u4 = *(const uint4*)&Tb[a];
#pragma unroll
    for (int e = 0; e < 8; ++e) {
      out.h8[e] = (bf16)S[e];
      S[e] = gs * S[e] + (float)in.h8[e];
    }
    *(uint4*)&Tb[a] = out.u4;
  }
}

// ---------------------------------------------------------------------------
// Phase C: per-(b,h,chunk) output:
// P = (q@k^T) * D(mask/decay);  o = P@v + (q * g^(i+1)) @ S_prev
//
// OCCUPANCY REWORK: Q and K fragments are dk-contiguous in GLOBAL memory, so
// they need no LDS at all (16B loads straight from L2-resident chunks).  Only
// V (c-contiguous fragments -> transpose, swz72) and P (cross-wave exchange)
// stay in LDS: 79 KB -> 27 KB, 2 -> 4 blocks/CU.  V-staging ds_writes overlap
// step-1 MFMA; ONE barrier covers both lVt and lP.  Step-3 decay folded in
// registers (dq hoisted per i-row).
// ---------------------------------------------------------------------------
__global__ __launch_bounds__(256) void chunk_out(
    const bf16* __restrict__ qb, const bf16* __restrict__ kb,
    const bf16* __restrict__ vb, const bf16* __restrict__ Sp,
    bf16* __restrict__ ob) {
  __shared__ bf16 lVt[128 * 72];  // [dv][c] (swizzled)
  __shared__ bf16 lP[64 * 72];    // [ci][cj] masked scores
  const int g = blockIdx.x;
  const int bh = g >> 6, n = g & 63, b = bh >> 3, h = bh & 7;
  const float log2g = log2f(1.0f - exp2f(-5.0f - (float)h));
  const int tid = threadIdx.x;
  const size_t rowbase = (size_t)(b * 4096 + n * 64) * 1024 + h * 128;
  const bf16* qc = qb + rowbase;
  const bf16* kc = kb + rowbase;
  const bf16* vc = vb + rowbase;

  // --- stage V -> lVt (transpose, swizzled); no barrier yet ---
#pragma unroll
  for (int s = 0; s < 4; ++s) {
    int u = tid + s * 256;
    int c = u >> 4, d0 = (u & 15) * 8;
    union { uint4 u4; bf16 h8[8]; } vv;
    vv.u4 = *(const uint4*)&vc[(size_t)c * 1024 + d0];
#pragma unroll
    for (int j = 0; j < 8; ++j) lVt[swz72(d0 + j, c)] = vv.h8[j];
  }

  const int w = tid >> 6, lane = tid & 63, lr = lane & 15, quad = lane >> 4;

  // --- Step 1: P = q @ k^T straight from global; wave w owns cols
  // [w*16, w*16+16).  Fragments are 16B dk-contiguous loads. ---
  f32x4 p[4] = {};
#pragma unroll
  for (int kk = 0; kk < 4; ++kk) {
    bf16x8 bfrag =
        *(const bf16x8*)&kc[(size_t)(w * 16 + lr) * 1024 + kk * 32 + quad * 8];
#pragma unroll
    for (int i = 0; i < 4; ++i) {
      bf16x8 afrag =
          *(const bf16x8*)&qc[(size_t)(i * 16 + lr) * 1024 + kk * 32 + quad * 8];
      p[i] = MFMA16(afrag, bfrag, p[i]);
    }
  }
  // mask + decay, write to lP (bf16)
#pragma unroll
  for (int i = 0; i < 4; ++i) {
#pragma unroll
    for (int r = 0; r < 4; ++r) {
      const int row = i * 16 + quad * 4 + r;
      const int col = w * 16 + lr;
      const int diff = row - col;
      const float val =
          (diff >= 0) ? p[i][r] * exp2f((float)diff * log2g) : 0.0f;
      lP[row * 72 + col] = (bf16)val;
    }
  }
  __syncthreads();  // covers lVt staging AND lP

  // --- Step 2: o_intra = P @ v; wave w covers dv in [w*32, w*32+32) ---
  f32x4 oacc[4][2] = {};
#pragma unroll
  for (int j = 0; j < 2; ++j) {
    const int dvt = w * 32 + j * 16;
#pragma unroll
    for (int kk = 0; kk < 2; ++kk) {
      bf16x8 bfrag = *(bf16x8*)&lVt[swz72(dvt + lr, kk * 32 + quad * 8)];
#pragma unroll
      for (int i = 0; i < 4; ++i) {
        bf16x8 afrag = *(bf16x8*)&lP[(i * 16 + lr) * 72 + kk * 32 + quad * 8];
        oacc[i][j] = MFMA16(afrag, bfrag, oacc[i][j]);
      }
    }
  }

  // --- Step 3: o_inter = (q * g^(ci+1)) @ S_prev.  Q refetched from global
  // (L2-hot), decay folded in registers; S^T rows are dk-contiguous. ---
  const bf16* sp = Sp + (size_t)g * 16384;
  float dqv[4];
#pragma unroll
  for (int i = 0; i < 4; ++i)
    dqv[i] = exp2f((float)(i * 16 + lr + 1) * log2g);
#pragma unroll
  for (int kk = 0; kk < 4; ++kk) {
    bf16x8 aN[4];
#pragma unroll
    for (int i = 0; i < 4; ++i) {
      bf16x8 a0 =
          *(const bf16x8*)&qc[(size_t)(i * 16 + lr) * 1024 + kk * 32 + quad * 8];
#pragma unroll
      for (int e = 0; e < 8; ++e) a0[e] = (bf16)((float)a0[e] * dqv[i]);
      aN[i] = a0;
    }
#pragma unroll
    for (int j = 0; j < 2; ++j) {
      bf16x8 bfrag =
          *(const bf16x8*)&sp[(size_t)(w * 32 + j * 16 + lr) * 128 + kk * 32 + quad * 8];
#pragma unroll
      for (int i = 0; i < 4; ++i) oacc[i][j] = MFMA16(aN[i], bfrag, oacc[i][j]);
    }
  }

  // --- write o chunk ---
  bf16* oc = ob + rowbase;
#pragma unroll
  for (int i = 0; i < 4; ++i)
#pragma unroll
    for (int j = 0; j < 2; ++j)
#pragma unroll
      for (int r = 0; r < 4; ++r) {
        const int row = i * 16 + quad * 4 + r;
        const int col = w * 32 + j * 16 + lr;
        oc[(size_t)row * 1024 + col] = (bf16)oacc[i][j][r];
      }
}

// ---------------------------------------------------------------------------
extern "C" void kernel_launch(void* const* d_in, const int* in_sizes, int n_in,
                              void* d_out, int out_size, void* d_ws,
                              size_t ws_size, hipStream_t stream) {
  const float* X  = (const float*)d_in[0];
  const float* Wq = (const float*)d_in[2];
  const float* Wk = (const float*)d_in[3];
  const float* Wv = (const float*)d_in[4];
  const float* Wo = (const float*)d_in[5];

  char* ws = (char*)d_ws;
  const size_t SZ_QKV = (size_t)8192 * 1024 * sizeof(bf16);  // 16 MiB each
  bf16* qb = (bf16*)(ws);                                    // q,k,v contiguous
  bf16* ob = (bf16*)(ws + 3 * SZ_QKV);
  bf16* Tb = (bf16*)(ws + 4 * SZ_QKV);                       // 32 MiB
  bf16* Wt = (bf16*)(ws + 6 * SZ_QKV);                       // 8 MiB
  bf16* Xb = (bf16*)(ws + 6 * SZ_QKV + (size_t)4 * 1024 * 1024 * sizeof(bf16));
  bf16* kb = qb + (size_t)8192 * 1024;
  bf16* vb = kb + (size_t)8192 * 1024;

  prep<<<5120, 256, 0, stream>>>(X, Wq, Wk, Wv, Wo, Xb, Wt);

  const float qscale = 0.08838834764831845f;  // 128^-0.5
  // fused q/k/v projection: z selects weight + output slice
  gemm_lds<bf16, 1><<<dim3(64, 8, 3), 256, 0, stream>>>(Xb, Wt, qb, qscale);

  chunk_kv<<<1024, 256, 0, stream>>>(kb, vb, Tb);
  scan_state<<<128, 256, 0, stream>>>(Tb);
  chunk_out<<<1024, 256, 0, stream>>>(qb, kb, vb, Tb, ob);

  gemm_lds<float, 0><<<dim3(64, 8), 256, 0, stream>>>(
      ob, Wt + (size_t)3 * 1024 * 1024, (float*)d_out, 1.0f);
}